// Round 1
// baseline (335.220 us; speedup 1.0000x reference)
//
#include <hip/hip_runtime.h>

#define NDIMC 2
#define NCELLS 1000
#define BATCHSZ 4
#define NSTEPS 251
#define XROW 2007   // 2 + NCELLS*NDIM + 5

__device__ __forceinline__ float fast_tanh(float x) {
    // tanh(x) = 1 - 2/(exp(2x)+1); exp(2x) = exp2(x * 2*log2(e))
    float e = __builtin_amdgcn_exp2f(x * 2.885390081777926774f);
    float r = __builtin_amdgcn_rcpf(e + 1.0f);
    return fmaf(-2.0f, r, 1.0f);   // exact ±1 saturation at large |x|
}

// Single-wave workgroup: LDS write->read ordering only needs the DS queue
// drained; "memory" clobber stops the compiler moving the ds ops across.
// No s_barrier, no vmcnt(0) drain (keeps the dw prefetch in flight).
#define LDS_FENCE() asm volatile("s_waitcnt lgkmcnt(0)" ::: "memory")

template<int N>
__device__ __forceinline__ float dotN(const float (&w)[N], const float* lds) {
    float a0 = 0.f, a1 = 0.f, a2 = 0.f, a3 = 0.f;
    #pragma unroll
    for (int c = 0; c < N; c += 16) {
        float4 v0 = *(const float4*)(lds + c);
        float4 v1 = *(const float4*)(lds + c + 4);
        float4 v2 = *(const float4*)(lds + c + 8);
        float4 v3 = *(const float4*)(lds + c + 12);
        a0 = fmaf(w[c+0],  v0.x, a0); a1 = fmaf(w[c+1],  v0.y, a1);
        a2 = fmaf(w[c+2],  v0.z, a2); a3 = fmaf(w[c+3],  v0.w, a3);
        a0 = fmaf(w[c+4],  v1.x, a0); a1 = fmaf(w[c+5],  v1.y, a1);
        a2 = fmaf(w[c+6],  v1.z, a2); a3 = fmaf(w[c+7],  v1.w, a3);
        a0 = fmaf(w[c+8],  v2.x, a0); a1 = fmaf(w[c+9],  v2.y, a1);
        a2 = fmaf(w[c+10], v2.z, a2); a3 = fmaf(w[c+11], v2.w, a3);
        a0 = fmaf(w[c+12], v3.x, a0); a1 = fmaf(w[c+13], v3.y, a1);
        a2 = fmaf(w[c+14], v3.z, a2); a3 = fmaf(w[c+15], v3.w, a3);
    }
    return (a0 + a1) + (a2 + a3);
}

__global__ __launch_bounds__(64, 2)
void phinn_sde_kernel(const float* __restrict__ x,   const float* __restrict__ dw,
                      const float* __restrict__ pw1, const float* __restrict__ pb1,
                      const float* __restrict__ pw2, const float* __restrict__ pb2,
                      const float* __restrict__ pw3, const float* __restrict__ pb3,
                      const float* __restrict__ pw4, const float* __restrict__ pb4,
                      const float* __restrict__ pw5, const float* __restrict__ pb5,
                      const float* __restrict__ tw,  const float* __restrict__ tb,
                      float* __restrict__ out)
{
    // stages: 0:h1(16) 1:h2(32) 2:h3(32) 3:g4pre(16) 4:g3pre(32) 5:g2pre(32)
    __shared__ float sh[2][6][32];

    const int tid  = threadIdx.x;
    const int sub  = tid & 31;          // lane within 32-group (= neuron id)
    const int grp  = tid >> 5;          // which of the wave's two cells
    const int s16  = sub & 15;
    const int b    = blockIdx.x / (NCELLS / 2);
    const int pair = blockIdx.x % (NCELLS / 2);
    const int cell = pair * 2 + grp;

    // ---- per-lane register-resident weights (loaded once, used 251x) ----
    const float r1a = pw1[s16 * 2 + 0];
    const float r1b = pw1[s16 * 2 + 1];
    const float rb1 = pb1[s16];

    float w2r[16];                       // pw2 row `sub` (16 in)
    #pragma unroll
    for (int k = 0; k < 16; ++k) w2r[k] = pw2[sub * 16 + k];
    const float rb2 = pb2[sub];

    float w3r[32];                       // pw3 row `sub`
    #pragma unroll
    for (int k = 0; k < 32; ++k) w3r[k] = pw3[sub * 32 + k];
    const float rb3 = pb3[sub];

    float w4r[32];                       // pw4 row `sub&15`
    #pragma unroll
    for (int k = 0; k < 32; ++k) w4r[k] = pw4[s16 * 32 + k];
    const float rb4 = pb4[s16];

    const float rw5 = pw5[s16];

    float w4c[16];                       // pw4 column `sub` (for g3)
    #pragma unroll
    for (int j = 0; j < 16; ++j) w4c[j] = pw4[j * 32 + sub];

    float w3c[32];                       // pw3 column `sub` (for g2)
    #pragma unroll
    for (int j = 0; j < 32; ++j) w3c[j] = pw3[j * 32 + sub];

    float w2c[32];                       // pw2 column `sub&15` (for g1)
    #pragma unroll
    for (int j = 0; j < 32; ++j) w2c[j] = pw2[j * 16 + s16];

    // ---- per-batch scalars & both tilt candidates ----
    const float* xb = x + (size_t)b * XROW;
    const float t0v    = xb[0];
    const float tcritv = xb[2 + NCELLS * NDIMC];       // index 2002
    const float p0x = xb[2003], p0y = xb[2004];
    const float p1x = xb[2005], p1y = xb[2006];
    // tilt[d] = sig0*tw[d][0] + sig1*tw[d][1] + tb[d]
    const float tA0 = fmaf(p0x, tw[0], fmaf(p0y, tw[1], tb[0]));
    const float tA1 = fmaf(p0x, tw[2], fmaf(p0y, tw[3], tb[1]));
    const float tB0 = fmaf(p1x, tw[0], fmaf(p1y, tw[1], tb[0]));
    const float tB1 = fmaf(p1x, tw[2], fmaf(p1y, tw[3], tb[1]));

    // cell state, replicated in all 32 lanes of the group
    float y0 = xb[2 + cell * 2 + 0];
    float y1 = xb[2 + cell * 2 + 1];

    const float* dwp = dw + ((size_t)b * NSTEPS * NCELLS + cell) * NDIMC;

    const float* l0 = &sh[grp][0][0];
    const float* l1 = &sh[grp][1][0];
    const float* l2 = &sh[grp][2][0];
    const float* l3 = &sh[grp][3][0];
    const float* l4 = &sh[grp][4][0];
    const float* l5 = &sh[grp][5][0];

    #pragma unroll 1
    for (int i = 0; i < NSTEPS; ++i) {
        // prefetch this step's noise early; consumed at the very end
        const float2 dwv = *(const float2*)dwp;
        dwp += NCELLS * NDIMC;
        const float t = t0v + 0.001f * (float)i;

        // ---------- forward ----------
        const float h1 = fast_tanh(fmaf(r1a, y0, fmaf(r1b, y1, rb1)));
        if (sub < 16) sh[grp][0][sub] = h1;
        LDS_FENCE();

        const float h2 = fast_tanh(dotN<16>(w2r, l0) + rb2);
        sh[grp][1][sub] = h2;
        LDS_FENCE();

        const float h3 = fast_tanh(dotN<32>(w3r, l1) + rb3);
        sh[grp][2][sub] = h3;
        LDS_FENCE();

        const float h4 = fast_tanh(dotN<32>(w4r, l2) + rb4);

        // ---------- backward (grad of sum(phi) wrt y) ----------
        const float g4p = rw5 * fmaf(-h4, h4, 1.0f);
        if (sub < 16) sh[grp][3][sub] = g4p;
        LDS_FENCE();

        const float g3p = dotN<16>(w4c, l3) * fmaf(-h3, h3, 1.0f);
        sh[grp][4][sub] = g3p;
        LDS_FENCE();

        const float g2p = dotN<32>(w3c, l4) * fmaf(-h2, h2, 1.0f);
        sh[grp][5][sub] = g2p;
        LDS_FENCE();

        const float g1p = dotN<32>(w2c, l5) * fmaf(-h1, h1, 1.0f);

        // gy[d] = sum_j pw1[j][d] * g1p[j]  (j = lanes 0..15; zero the rest)
        float v0 = (sub < 16) ? r1a * g1p : 0.0f;
        float v1 = (sub < 16) ? r1b * g1p : 0.0f;
        #pragma unroll
        for (int m = 1; m < 32; m <<= 1) {
            v0 += __shfl_xor(v0, m, 64);
            v1 += __shfl_xor(v1, m, 64);
        }

        // ---------- update ----------
        const bool  cnd   = t < tcritv;
        const float tilt0 = cnd ? tA0 : tB0;
        const float tilt1 = cnd ? tA1 : tB1;
        y0 = fmaf(-0.001f, v0 + tilt0, fmaf(0.001f, dwv.x, y0));
        y1 = fmaf(-0.001f, v1 + tilt1, fmaf(0.001f, dwv.y, y1));
    }

    if (sub == 0) {
        *(float2*)(out + ((size_t)b * NCELLS + cell) * NDIMC) = make_float2(y0, y1);
    }
}

extern "C" void kernel_launch(void* const* d_in, const int* in_sizes, int n_in,
                              void* d_out, int out_size, void* d_ws, size_t ws_size,
                              hipStream_t stream) {
    const float* x   = (const float*)d_in[0];
    const float* dw  = (const float*)d_in[1];
    const float* pw1 = (const float*)d_in[2];
    const float* pb1 = (const float*)d_in[3];
    const float* pw2 = (const float*)d_in[4];
    const float* pb2 = (const float*)d_in[5];
    const float* pw3 = (const float*)d_in[6];
    const float* pb3 = (const float*)d_in[7];
    const float* pw4 = (const float*)d_in[8];
    const float* pb4 = (const float*)d_in[9];
    const float* pw5 = (const float*)d_in[10];
    const float* pb5 = (const float*)d_in[11];
    const float* tw  = (const float*)d_in[12];
    const float* tb  = (const float*)d_in[13];
    float* out = (float*)d_out;

    dim3 grid(BATCHSZ * NCELLS / 2);   // 2000 single-wave blocks (2 cells each)
    dim3 block(64);
    phinn_sde_kernel<<<grid, block, 0, stream>>>(x, dw, pw1, pb1, pw2, pb2,
                                                 pw3, pb3, pw4, pb4, pw5, pb5,
                                                 tw, tb, out);
}